// Round 1
// baseline (506.343 us; speedup 1.0000x reference)
//
#include <hip/hip_runtime.h>

#define N_ROWS 16384
#define K_CB   8192
#define D_DIM  64
#define SPLIT  16     // k-chunks over gridDim.y
#define TK     128    // codebook rows per LDS tile (32 KB)
#define BLOCK  256

// ---------------- kernel 0: codebook squared norms ----------------
__global__ void vq_csq_kernel(const float* __restrict__ cb, float* __restrict__ csq) {
    int k = blockIdx.x * blockDim.x + threadIdx.x;
    if (k >= K_CB) return;
    const float4* row = (const float4*)(cb + (size_t)k * D_DIM);
    float s0 = 0.f, s1 = 0.f, s2 = 0.f, s3 = 0.f;
#pragma unroll
    for (int i = 0; i < D_DIM / 4; ++i) {
        float4 v = row[i];
        s0 += v.x * v.x; s1 += v.y * v.y; s2 += v.z * v.z; s3 += v.w * v.w;
    }
    csq[k] = (s0 + s1) + (s2 + s3);
}

// ---------------- kernel 1: partial argmin over a K-chunk ----------------
__global__ __launch_bounds__(BLOCK) void vq_phaseA_kernel(
    const float* __restrict__ enc, const float* __restrict__ cb,
    const float* __restrict__ csq,
    float* __restrict__ bestd, int* __restrict__ besti)
{
    __shared__ float lds[TK * D_DIM];   // 32 KB

    const int row    = blockIdx.x * BLOCK + threadIdx.x;
    const int kbase0 = blockIdx.y * (K_CB / SPLIT);

    // row vector into registers (64 VGPRs)
    float x[D_DIM];
    const float4* xr = (const float4*)(enc + (size_t)row * D_DIM);
#pragma unroll
    for (int i = 0; i < D_DIM / 4; ++i) {
        float4 v = xr[i];
        x[4*i+0] = v.x; x[4*i+1] = v.y; x[4*i+2] = v.z; x[4*i+3] = v.w;
    }

    float best = INFINITY;
    int   bidx = 0;

    const int ntiles = (K_CB / SPLIT) / TK;
    for (int t = 0; t < ntiles; ++t) {
        const int kbase = kbase0 + t * TK;
        // cooperative staging: TK*64 floats, coalesced float4
        const float4* src = (const float4*)(cb + (size_t)kbase * D_DIM);
        float4* dst = (float4*)lds;
#pragma unroll
        for (int i = 0; i < (TK * D_DIM / 4) / BLOCK; ++i)
            dst[threadIdx.x + i * BLOCK] = src[threadIdx.x + i * BLOCK];
        __syncthreads();

#pragma unroll 2
        for (int kk = 0; kk < TK; ++kk) {
            const float4* c = (const float4*)(lds + kk * D_DIM);
            float d0 = 0.f, d1 = 0.f, d2 = 0.f, d3 = 0.f;
#pragma unroll
            for (int i = 0; i < D_DIM / 4; ++i) {
                float4 v = c[i];     // wave-uniform address -> LDS broadcast, no conflicts
                d0 += x[4*i+0] * v.x;
                d1 += x[4*i+1] * v.y;
                d2 += x[4*i+2] * v.z;
                d3 += x[4*i+3] * v.w;
            }
            const float dot  = (d0 + d1) + (d2 + d3);
            const float dist = csq[kbase + kk] - 2.0f * dot;  // ||x||^2 constant per row: dropped
            if (dist < best) { best = dist; bidx = kbase + kk; }
        }
        __syncthreads();
    }

    bestd[blockIdx.y * N_ROWS + row] = best;
    besti[blockIdx.y * N_ROWS + row] = bidx;
}

// ---------------- kernel 2: reduce splits + gather codeword ----------------
__global__ void vq_phaseB_kernel(const float* __restrict__ cb,
                                 const float* __restrict__ bestd,
                                 const int* __restrict__ besti,
                                 float* __restrict__ out)
{
    const int wave = threadIdx.x >> 6;            // 4 waves / block
    const int lane = threadIdx.x & 63;
    const int row  = blockIdx.x * 4 + wave;

    int bidx = 0;
    if (lane == 0) {
        float best = INFINITY;
        for (int s = 0; s < SPLIT; ++s) {         // ascending s => ascending k: first-min wins
            float d = bestd[s * N_ROWS + row];
            if (d < best) { best = d; bidx = besti[s * N_ROWS + row]; }
        }
    }
    bidx = __shfl(bidx, 0, 64);
    out[(size_t)row * D_DIM + lane] = cb[(size_t)bidx * D_DIM + lane];
}

extern "C" void kernel_launch(void* const* d_in, const int* in_sizes, int n_in,
                              void* d_out, int out_size, void* d_ws, size_t ws_size,
                              hipStream_t stream) {
    const float* enc = (const float*)d_in[0];   // (16,32,32,64) fp32 = 16384 x 64
    const float* cb  = (const float*)d_in[1];   // (8192,64) fp32
    float* out = (float*)d_out;

    // workspace layout (~2.03 MB): csq[K] | bestd[SPLIT*N] | besti[SPLIT*N]
    float* csq   = (float*)d_ws;
    float* bestd = csq + K_CB;
    int*   besti = (int*)(bestd + SPLIT * N_ROWS);

    vq_csq_kernel<<<K_CB / 256, 256, 0, stream>>>(cb, csq);

    dim3 gA(N_ROWS / BLOCK, SPLIT);
    vq_phaseA_kernel<<<gA, BLOCK, 0, stream>>>(enc, cb, csq, bestd, besti);

    vq_phaseB_kernel<<<N_ROWS / 4, 256, 0, stream>>>(cb, bestd, besti, out);
}